// Round 9
// baseline (391.938 us; speedup 1.0000x reference)
//
#include <hip/hip_runtime.h>

// GraphSAGE 2-layer. N=50000, E=800000, 128 -> 256 -> 256.
// Round 18: revert k_mfma3 (B-direct regressed 4x: latency-bound, 17% occ) to
// round-13 k_mfma2 (LDS-staged A+B, known good). New: XCD channel-sliced
// gathers. Block b -> slice b%8 (32ch, 64B) of node group b/8; round-robin
// dispatch puts slice s on XCD s; per-XCD slice working set = NN*64B = 3.2MB
// fits the 4MB L2 -> each h1b byte consumed by exactly ONE XCD (fabric
// traffic 175MB -> ~26MB compulsory; reuse becomes local L2 hits).
// Wave = 2 nodes (32-lane halves, shfl width 32), ushort channel loads.

#define NN 50000
#define NE 800000

typedef __bf16 v8bf __attribute__((ext_vector_type(8)));
typedef float v4f __attribute__((ext_vector_type(4)));
typedef float nf4 __attribute__((ext_vector_type(4)));
typedef unsigned nu2 __attribute__((ext_vector_type(2)));

__device__ __forceinline__ unsigned short f2b(float f) {
    unsigned u = __float_as_uint(f);
    return (unsigned short)((u + 0x7FFFu + ((u >> 16) & 1u)) >> 16);
}
__device__ __forceinline__ float b2f(unsigned short h) {
    return __uint_as_float(((unsigned)h) << 16);
}
__device__ __forceinline__ unsigned pack2(float a, float b) {
    return (unsigned)f2b(a) | ((unsigned)f2b(b) << 16);
}

// Fused hist + prep. Sections by blockIdx (256 threads each), hist FIRST so
// its atomic-bound phase overlaps the streaming casts behind it.
#define PH_HIST 782
#define PH_BT0 256
#define PH_BT1 512
#define PH_XB  6250
#define CREP 50048
__global__ __launch_bounds__(256) void k_preph(const float* __restrict__ x,
                                               const float* __restrict__ Wl0,
                                               const float* __restrict__ Wr0,
                                               const float* __restrict__ Wl1,
                                               const float* __restrict__ Wr1,
                                               const int* __restrict__ dst,
                                               int* __restrict__ cnt4,
                                               int* __restrict__ rank,
                                               unsigned short* __restrict__ Bt0,
                                               unsigned short* __restrict__ Bt1,
                                               unsigned short* __restrict__ xb) {
    int b = blockIdx.x;
    int tid = threadIdx.x;
    if (b < PH_HIST) {
        int e = b * 1024 + tid;                         // 4 edges/thread, stride 256
        int* cr = cnt4 + ((tid >> 6) & 3) * CREP;       // replica = (e>>6)&3
        if (e + 768 < NE) {
            int d0 = __builtin_nontemporal_load(dst + e);
            int d1 = __builtin_nontemporal_load(dst + e + 256);
            int d2 = __builtin_nontemporal_load(dst + e + 512);
            int d3 = __builtin_nontemporal_load(dst + e + 768);
            int p0 = atomicAdd(&cr[d0], 1);
            int p1 = atomicAdd(&cr[d1], 1);
            int p2 = atomicAdd(&cr[d2], 1);
            int p3 = atomicAdd(&cr[d3], 1);
            __builtin_nontemporal_store(p0, rank + e);
            __builtin_nontemporal_store(p1, rank + e + 256);
            __builtin_nontemporal_store(p2, rank + e + 512);
            __builtin_nontemporal_store(p3, rank + e + 768);
        } else {
#pragma unroll
            for (int i = 0; i < 4; ++i) {
                int ee = e + i * 256;
                if (ee < NE) {
                    int d = __builtin_nontemporal_load(dst + ee);
                    int pos = atomicAdd(&cr[d], 1);
                    __builtin_nontemporal_store(pos, rank + ee);
                }
            }
        }
    } else if (b < PH_HIST + PH_BT0) {
        int idx = (b - PH_HIST) * 256 + tid;            // [0, 65536)
        int n = idx >> 8, k = idx & 255;
        float v = (k < 128) ? Wl0[(size_t)k * 256 + n] : Wr0[(size_t)(k - 128) * 256 + n];
        Bt0[idx] = f2b(v);
    } else if (b < PH_HIST + PH_BT0 + PH_BT1) {
        int idx = (b - PH_HIST - PH_BT0) * 256 + tid;   // [0, 131072)
        int n = idx >> 9, k = idx & 511;
        float v = (k < 256) ? Wl1[(size_t)k * 256 + n] : Wr1[(size_t)(k - 256) * 256 + n];
        Bt1[idx] = f2b(v);
    } else {
        int i4 = (b - PH_HIST - PH_BT0 - PH_BT1) * 256 + tid;  // [0, 1.6M)
        nf4 v = __builtin_nontemporal_load((const nf4*)x + i4);
        nu2 o;
        o.x = pack2(v.x, v.y);
        o.y = pack2(v.z, v.w);
        *((nu2*)xb + i4) = o;
    }
}

// Fused scan: 49 blocks x 1024. Sums 4 replica counts; per-block LDS scan of
// totals; chunk sums via atomic flags. Emits rp, rp4, dinv.
__global__ __launch_bounds__(1024) void k_scanf(const int* __restrict__ cnt4,
                                                int* __restrict__ bsum,
                                                int* __restrict__ rp,
                                                int4* __restrict__ rp4,
                                                float* __restrict__ dinv) {
    __shared__ int tmp[1024];
    __shared__ int s_off;
    const int b = blockIdx.x, tid = threadIdx.x;
    const int gid = b * 1024 + tid;
    int c0 = 0, c1 = 0, c2 = 0, c3 = 0;
    if (gid < NN) {
        c0 = cnt4[gid];
        c1 = cnt4[CREP + gid];
        c2 = cnt4[2 * CREP + gid];
        c3 = cnt4[3 * CREP + gid];
    }
    int v = c0 + c1 + c2 + c3;
    tmp[tid] = v;
    __syncthreads();
    for (int off = 1; off < 1024; off <<= 1) {
        int t = (tid >= off) ? tmp[tid - off] : 0;
        __syncthreads();
        tmp[tid] += t;
        __syncthreads();
    }
    if (tid == 1023) atomicExch(&bsum[b], tmp[1023] + 1);   // publish (nonzero)
    if (tid == 0) {
        int off = 0;
        for (int i = 0; i < b; ++i) {
            int val;
            while ((val = atomicAdd(&bsum[i], 0)) == 0) {}
            off += val - 1;
        }
        s_off = off;
    }
    __syncthreads();
    if (gid < NN) {
        int base = tmp[tid] - v + s_off;
        rp[gid] = base;
        rp4[gid] = make_int4(base, base + c0, base + c0 + c1, base + c0 + c1 + c2);
        dinv[gid] = 1.0f / fmaxf((float)v, 1.0f);
    }
    if (gid == 0) rp[NN] = NE;
}

// Atomic-free bucket: pos = rp4[dst].sel(replica) + rank. 4 edges/thread.
__global__ __launch_bounds__(256) void k_bucket(const int* __restrict__ src,
                                                const int* __restrict__ dst,
                                                const float* __restrict__ ew,
                                                const int* __restrict__ rank,
                                                const int4* __restrict__ rp4,
                                                int2* __restrict__ epk) {
    int base = blockIdx.x * 1024 + threadIdx.x;
    int rep = (threadIdx.x >> 6) & 3;                    // == (e>>6)&3 for all i
#pragma unroll
    for (int i = 0; i < 4; ++i) {
        int e = base + i * 256;
        if (e < NE) {
            int d = __builtin_nontemporal_load(dst + e);
            int r = __builtin_nontemporal_load(rank + e);
            int s = __builtin_nontemporal_load(src + e);
            float w = __builtin_nontemporal_load(ew + e);
            int4 q = rp4[d];
            int off = (rep == 0) ? q.x : (rep == 1) ? q.y : (rep == 2) ? q.z : q.w;
            epk[off + r] = make_int2(s, __float_as_int(w));
        }
    }
}

// gather0x: XCD channel-sliced. Block b: slot=b&7 (XCD), slice=slot&3 (32ch of
// 128), node group = (b>>3)*2 + (slot>>2). 4 waves x 2 nodes (32-lane halves).
// Per-XCD slice working set = NN*64B = 3.2MB -> L2-resident.
__global__ __launch_bounds__(256) void k_gather0x(const unsigned short* __restrict__ xb,
                                                  const int* __restrict__ rp,
                                                  const int2* __restrict__ epk,
                                                  const float* __restrict__ dinv,
                                                  unsigned short* __restrict__ aggb) {
    const int b = blockIdx.x;
    const int slot = b & 7;
    const int slice = slot & 3;
    const int g = (b >> 3) * 2 + (slot >> 2);      // [0, 6250)
    const int tid = threadIdx.x;
    const int w = tid >> 6, lane = tid & 63;
    const int half = lane >> 5, l32 = lane & 31;
    const int node = g * 8 + w * 2 + half;
    const int c = slice * 32 + l32;
    const bool valid = node < NN;
    int beg = 0, n = 0;
    float di = 0.f;
    if (valid) { beg = rp[node]; n = rp[node + 1] - beg; di = dinv[node]; }
    const int nOther = __shfl(n, (lane + 32) & 63);
    const int nmax = max(n, nOther);
    float acc = 0.f;
    for (int eb = 0; eb < nmax; eb += 32) {
        const int nh = n - eb;                      // may be <= 0
        int idx = beg + eb + min(l32, max(nh - 1, 0));
        idx = min(idx, NE - 1);
        const int2 pk = epk[idx];
        const int jm = min(nmax - eb, 32);
        int j = 0;
        for (; j + 7 < jm; j += 8) {
            int s[8]; float wt[8];
#pragma unroll
            for (int i = 0; i < 8; ++i) {
                s[i] = __shfl(pk.x, j + i, 32);
                float ww = __int_as_float(__shfl(pk.y, j + i, 32));
                wt[i] = (j + i < nh) ? ww : 0.f;
            }
            unsigned short u[8];
#pragma unroll
            for (int i = 0; i < 8; ++i)
                u[i] = xb[(size_t)s[i] * 128 + c];
#pragma unroll
            for (int i = 0; i < 8; ++i)
                acc += wt[i] * b2f(u[i]);
        }
        for (; j < jm; ++j) {
            int s = __shfl(pk.x, j, 32);
            float ww = __int_as_float(__shfl(pk.y, j, 32));
            unsigned short u = xb[(size_t)s * 128 + c];
            acc += ((j < nh) ? ww : 0.f) * b2f(u);
        }
    }
    if (valid) aggb[(size_t)node * 128 + c] = f2b(acc * di);
}

// gather1x: XCD channel-sliced. Block b: slice=b&7 (32ch of 256), node group
// b>>3. 4 waves x 2 nodes. Per-XCD slice working set = NN*64B = 3.2MB.
__global__ __launch_bounds__(256) void k_gather1x(const unsigned short* __restrict__ h,
                                                  const int* __restrict__ rp,
                                                  const int2* __restrict__ epk,
                                                  const float* __restrict__ dinv,
                                                  unsigned short* __restrict__ aggb) {
    const int b = blockIdx.x;
    const int slice = b & 7;
    const int g = b >> 3;                          // [0, 6250)
    const int tid = threadIdx.x;
    const int w = tid >> 6, lane = tid & 63;
    const int half = lane >> 5, l32 = lane & 31;
    const int node = g * 8 + w * 2 + half;
    const int c = slice * 32 + l32;
    const bool valid = node < NN;
    int beg = 0, n = 0;
    float di = 0.f;
    if (valid) { beg = rp[node]; n = rp[node + 1] - beg; di = dinv[node]; }
    const int nOther = __shfl(n, (lane + 32) & 63);
    const int nmax = max(n, nOther);
    float acc = 0.f;
    for (int eb = 0; eb < nmax; eb += 32) {
        const int nh = n - eb;
        int idx = beg + eb + min(l32, max(nh - 1, 0));
        idx = min(idx, NE - 1);
        const int2 pk = epk[idx];
        const int jm = min(nmax - eb, 32);
        int j = 0;
        for (; j + 7 < jm; j += 8) {
            int s[8]; float wt[8];
#pragma unroll
            for (int i = 0; i < 8; ++i) {
                s[i] = __shfl(pk.x, j + i, 32);
                float ww = __int_as_float(__shfl(pk.y, j + i, 32));
                wt[i] = (j + i < nh) ? ww : 0.f;
            }
            unsigned short u[8];
#pragma unroll
            for (int i = 0; i < 8; ++i)
                u[i] = h[(size_t)s[i] * 256 + c];
#pragma unroll
            for (int i = 0; i < 8; ++i)
                acc += wt[i] * b2f(u[i]);
        }
        for (; j < jm; ++j) {
            int s = __shfl(pk.x, j, 32);
            float ww = __int_as_float(__shfl(pk.y, j, 32));
            unsigned short u = h[(size_t)s * 256 + c];
            acc += ((j < nh) ? ww : 0.f) * b2f(u);
        }
    }
    if (valid) aggb[(size_t)node * 256 + c] = f2b(acc * di);
}

// MFMA GEMM: C[row, 0:256] = concat(Aagg[row,:], Aself[row,:]) @ Bt^T + bias.
// 128x256 (full-N) tile per block, 512 threads / 8 waves (4M x 2N).
// (round-13 k_mfma2, known good)
template <int K0, bool OUT_F32, bool RELU>
__global__ __launch_bounds__(512) void k_mfma2(const unsigned short* __restrict__ Aagg,
                                               const unsigned short* __restrict__ Aself,
                                               const unsigned short* __restrict__ Bt,
                                               const float* __restrict__ bias,
                                               void* __restrict__ outp) {
    __shared__ unsigned short As[128 * 32];
    __shared__ unsigned short Bs[256 * 32];
    const int tid = threadIdx.x;
    const int m0 = blockIdx.x * 128;
    const int K = 2 * K0;
    const int lane = tid & 63;
    const int w = tid >> 6;
    const int wr = w >> 1, wc = w & 1;          // 4 M-waves x 2 N-waves
    const int fr = lane & 15, fq = lane >> 4;
    const int srowA = tid >> 2;                  // 0..127
    const int sckA = (tid & 3) * 8;              // k-chunk of 8
    const int srowB = tid >> 1;                  // 0..255
    const int sckB = (tid & 1) * 16;             // two uint4: k and k+8

    v4f acc[2][8];
#pragma unroll
    for (int mi = 0; mi < 2; ++mi)
#pragma unroll
        for (int ni = 0; ni < 8; ++ni)
            acc[mi][ni] = (v4f){0.f, 0.f, 0.f, 0.f};

    for (int k0 = 0; k0 < K; k0 += 32) {
        // register-stage global loads
        const int kkA = k0 + sckA;
        const unsigned short* Asrc = (kkA < K0) ? Aagg : (Aself - K0);
        const int rA = m0 + srowA;
        uint4 av = make_uint4(0, 0, 0, 0);
        if (rA < NN) av = *(const uint4*)(Asrc + (size_t)rA * K0 + kkA);
        uint4 bv0 = *(const uint4*)(Bt + (size_t)srowB * K + k0 + sckB);
        uint4 bv1 = *(const uint4*)(Bt + (size_t)srowB * K + k0 + sckB + 8);

        __syncthreads();
        *(uint4*)(As + srowA * 32 + sckA) = av;
        *(uint4*)(Bs + srowB * 32 + sckB) = bv0;
        *(uint4*)(Bs + srowB * 32 + sckB + 8) = bv1;
        __syncthreads();

        v8bf a[2], b[8];
#pragma unroll
        for (int mi = 0; mi < 2; ++mi)
            a[mi] = *(const v8bf*)(As + (wr * 32 + mi * 16 + fr) * 32 + fq * 8);
#pragma unroll
        for (int ni = 0; ni < 8; ++ni)
            b[ni] = *(const v8bf*)(Bs + (wc * 128 + ni * 16 + fr) * 32 + fq * 8);
#pragma unroll
        for (int mi = 0; mi < 2; ++mi)
#pragma unroll
            for (int ni = 0; ni < 8; ++ni)
                acc[mi][ni] = __builtin_amdgcn_mfma_f32_16x16x32_bf16(a[mi], b[ni], acc[mi][ni], 0, 0, 0);
    }

#pragma unroll
    for (int mi = 0; mi < 2; ++mi) {
#pragma unroll
        for (int ni = 0; ni < 8; ++ni) {
            const int col = wc * 128 + ni * 16 + fr;
            const float bb = bias[col];
#pragma unroll
            for (int r = 0; r < 4; ++r) {
                const int row = m0 + wr * 32 + mi * 16 + fq * 4 + r;
                if (row < NN) {
                    float v = acc[mi][ni][r] + bb;
                    if (RELU) v = fmaxf(v, 0.f);
                    if (OUT_F32)
                        __builtin_nontemporal_store(v, &((float*)outp)[(size_t)row * 256 + col]);
                    else
                        ((unsigned short*)outp)[(size_t)row * 256 + col] = f2b(v);
                }
            }
        }
    }
}

extern "C" void kernel_launch(void* const* d_in, const int* in_sizes, int n_in,
                              void* d_out, int out_size, void* d_ws, size_t ws_size,
                              hipStream_t stream) {
    const float* x   = (const float*)d_in[0];
    const int*   ei  = (const int*)d_in[1];
    const float* ew  = (const float*)d_in[2];
    const float* Wl0 = (const float*)d_in[3];
    const float* Wr0 = (const float*)d_in[4];
    const float* b0  = (const float*)d_in[5];
    const float* Wl1 = (const float*)d_in[6];
    const float* Wr1 = (const float*)d_in[7];
    const float* b1  = (const float*)d_in[8];
    float* out = (float*)d_out;

    const int* src = ei;
    const int* dst = ei + NE;

    // ws layout (bytes), total ~58.6 MB (unchanged):
    //   0        dinv  f32[50000]
    //   409600   rp    int[50001]
    //   614400   epk   int2[800000]
    //   7014400  Bt0   bf16[256*256]
    //   7145472  Bt1   bf16[256*512]
    //   7407616  h1b   bf16[50000*256]; head aliases scratch dead before
    //            mfma0 writes h1b: rank int[800000] @ +0 (3.2MB),
    //            cnt4 int[4*50048]+bsum @ +3,200,000, rp4 int4[50000]
    //            @ +4,224,000.
    //   33007616 aggb  bf16[50000*256]; layer0: agg=[NN][128], xb in 2nd half
    char* ws = (char*)d_ws;
    float*          dinv = (float*)(ws + 0);
    int*            rp   = (int*)(ws + 409600);
    int2*           epk  = (int2*)(ws + 614400);
    unsigned short* Bt0  = (unsigned short*)(ws + 7014400);
    unsigned short* Bt1  = (unsigned short*)(ws + 7145472);
    unsigned short* h1b  = (unsigned short*)(ws + 7407616);
    int*            rank = (int*)h1b;
    int*            cnt4 = (int*)((char*)h1b + 3200000);
    int*            bsum = cnt4 + 4 * CREP;
    int4*           rp4  = (int4*)((char*)h1b + 4224000);
    unsigned short* aggb = (unsigned short*)(ws + 33007616);
    unsigned short* xb   = aggb + (size_t)NN * 128;

    (void)hipMemsetAsync(cnt4, 0, 4 * CREP * 4 + 256, stream);  // zeros cnt4 + bsum
    k_preph<<<PH_HIST + PH_BT0 + PH_BT1 + PH_XB, 256, 0, stream>>>(
        x, Wl0, Wr0, Wl1, Wr1, dst, cnt4, rank, Bt0, Bt1, xb);
    k_scanf<<<49, 1024, 0, stream>>>(cnt4, bsum, rp, rp4, dinv);
    k_bucket<<<(NE + 1023) / 1024, 256, 0, stream>>>(src, dst, ew, rank, rp4, epk);

    const int gm = (NN + 127) / 128;
    // layer 0: 3125*8 = 25000 blocks (slice in low 3 bits -> XCD affinity)
    k_gather0x<<<25000, 256, 0, stream>>>(xb, rp, (const int2*)epk, dinv, aggb);
    k_mfma2<128, false, true><<<gm, 512, 0, stream>>>(aggb, xb, Bt0, b0, h1b);
    // layer 1: 6250*8 = 50000 blocks
    k_gather1x<<<50000, 256, 0, stream>>>(h1b, rp, (const int2*)epk, dinv, aggb);
    k_mfma2<256, true, false><<<gm, 512, 0, stream>>>(aggb, h1b, Bt1, b1, out);
}

// Round 10
// 375.215 us; speedup vs baseline: 1.0446x; 1.0446x over previous
//
#include <hip/hip_runtime.h>

// GraphSAGE 2-layer. N=50000, E=800000, 128 -> 256 -> 256.
// Round 19: revert round-18 channel-sliced gathers (FETCH rose 175->211MB,
// no XCD locality materialized, 2B loads made it VALU-bound). Back to the
// round-14 config (314us). One change: k_scanf + k_bucket merged into
// k_scanbkt — 49 co-resident blocks scan, device-fence + done-counter grid
// barrier, then bucket 800K edges (16/thread). One fewer dispatch + gap.

#define NN 50000
#define NE 800000

typedef __bf16 v8bf __attribute__((ext_vector_type(8)));
typedef float v4f __attribute__((ext_vector_type(4)));
typedef float nf4 __attribute__((ext_vector_type(4)));
typedef unsigned nu2 __attribute__((ext_vector_type(2)));

__device__ __forceinline__ unsigned short f2b(float f) {
    unsigned u = __float_as_uint(f);
    return (unsigned short)((u + 0x7FFFu + ((u >> 16) & 1u)) >> 16);
}
__device__ __forceinline__ float b2f(unsigned short h) {
    return __uint_as_float(((unsigned)h) << 16);
}
__device__ __forceinline__ unsigned pack2(float a, float b) {
    return (unsigned)f2b(a) | ((unsigned)f2b(b) << 16);
}

// Fused hist + prep. Sections by blockIdx (256 threads each), hist FIRST so
// its atomic-bound phase overlaps the streaming casts behind it.
#define PH_HIST 782
#define PH_BT0 256
#define PH_BT1 512
#define PH_XB  6250
#define CREP 50048
__global__ __launch_bounds__(256) void k_preph(const float* __restrict__ x,
                                               const float* __restrict__ Wl0,
                                               const float* __restrict__ Wr0,
                                               const float* __restrict__ Wl1,
                                               const float* __restrict__ Wr1,
                                               const int* __restrict__ dst,
                                               int* __restrict__ cnt4,
                                               int* __restrict__ rank,
                                               unsigned short* __restrict__ Bt0,
                                               unsigned short* __restrict__ Bt1,
                                               unsigned short* __restrict__ xb) {
    int b = blockIdx.x;
    int tid = threadIdx.x;
    if (b < PH_HIST) {
        int e = b * 1024 + tid;                         // 4 edges/thread, stride 256
        int* cr = cnt4 + ((tid >> 6) & 3) * CREP;       // replica = (e>>6)&3
        if (e + 768 < NE) {
            int d0 = __builtin_nontemporal_load(dst + e);
            int d1 = __builtin_nontemporal_load(dst + e + 256);
            int d2 = __builtin_nontemporal_load(dst + e + 512);
            int d3 = __builtin_nontemporal_load(dst + e + 768);
            int p0 = atomicAdd(&cr[d0], 1);
            int p1 = atomicAdd(&cr[d1], 1);
            int p2 = atomicAdd(&cr[d2], 1);
            int p3 = atomicAdd(&cr[d3], 1);
            __builtin_nontemporal_store(p0, rank + e);
            __builtin_nontemporal_store(p1, rank + e + 256);
            __builtin_nontemporal_store(p2, rank + e + 512);
            __builtin_nontemporal_store(p3, rank + e + 768);
        } else {
#pragma unroll
            for (int i = 0; i < 4; ++i) {
                int ee = e + i * 256;
                if (ee < NE) {
                    int d = __builtin_nontemporal_load(dst + ee);
                    int pos = atomicAdd(&cr[d], 1);
                    __builtin_nontemporal_store(pos, rank + ee);
                }
            }
        }
    } else if (b < PH_HIST + PH_BT0) {
        int idx = (b - PH_HIST) * 256 + tid;            // [0, 65536)
        int n = idx >> 8, k = idx & 255;
        float v = (k < 128) ? Wl0[(size_t)k * 256 + n] : Wr0[(size_t)(k - 128) * 256 + n];
        Bt0[idx] = f2b(v);
    } else if (b < PH_HIST + PH_BT0 + PH_BT1) {
        int idx = (b - PH_HIST - PH_BT0) * 256 + tid;   // [0, 131072)
        int n = idx >> 9, k = idx & 511;
        float v = (k < 256) ? Wl1[(size_t)k * 256 + n] : Wr1[(size_t)(k - 256) * 256 + n];
        Bt1[idx] = f2b(v);
    } else {
        int i4 = (b - PH_HIST - PH_BT0 - PH_BT1) * 256 + tid;  // [0, 1.6M)
        nf4 v = __builtin_nontemporal_load((const nf4*)x + i4);
        nu2 o;
        o.x = pack2(v.x, v.y);
        o.y = pack2(v.z, v.w);
        *((nu2*)xb + i4) = o;
    }
}

// Merged scan + bucket: 49 blocks x 1024, all co-resident.
// Phase A: sum 4 replica counts, per-block LDS scan, chunk offsets via atomic
// flags (bsum[0..48]); emit rp, rp4, dinv. Grid barrier: threadfence + done
// counter at bsum[63]. Phase B: bucket 800K edges, 16/thread.
__global__ __launch_bounds__(1024) void k_scanbkt(const int* __restrict__ cnt4,
                                                  int* __restrict__ bsum,
                                                  int* __restrict__ rp,
                                                  int4* __restrict__ rp4,
                                                  float* __restrict__ dinv,
                                                  const int* __restrict__ src,
                                                  const int* __restrict__ dst,
                                                  const float* __restrict__ ew,
                                                  const int* __restrict__ rank,
                                                  int2* __restrict__ epk) {
    __shared__ int tmp[1024];
    __shared__ int s_off;
    const int b = blockIdx.x, tid = threadIdx.x;
    const int gid = b * 1024 + tid;
    int c0 = 0, c1 = 0, c2 = 0, c3 = 0;
    if (gid < NN) {
        c0 = cnt4[gid];
        c1 = cnt4[CREP + gid];
        c2 = cnt4[2 * CREP + gid];
        c3 = cnt4[3 * CREP + gid];
    }
    int v = c0 + c1 + c2 + c3;
    tmp[tid] = v;
    __syncthreads();
    for (int off = 1; off < 1024; off <<= 1) {
        int t = (tid >= off) ? tmp[tid - off] : 0;
        __syncthreads();
        tmp[tid] += t;
        __syncthreads();
    }
    if (tid == 1023) atomicExch(&bsum[b], tmp[1023] + 1);   // publish (nonzero)
    if (tid == 0) {
        int off = 0;
        for (int i = 0; i < b; ++i) {
            int val;
            while ((val = atomicAdd(&bsum[i], 0)) == 0) {}
            off += val - 1;
        }
        s_off = off;
    }
    __syncthreads();
    if (gid < NN) {
        int base = tmp[tid] - v + s_off;
        rp[gid] = base;
        rp4[gid] = make_int4(base, base + c0, base + c0 + c1, base + c0 + c1 + c2);
        dinv[gid] = 1.0f / fmaxf((float)v, 1.0f);
    }
    if (gid == 0) rp[NN] = NE;

    // ---- grid barrier: all rp4 stores visible before any bucket read ----
    __threadfence();
    __syncthreads();
    if (tid == 0) {
        atomicAdd(&bsum[63], 1);
        while (atomicAdd(&bsum[63], 0) < 49) {}
    }
    __syncthreads();

    // ---- Phase B: bucket. e strided by 49*1024; ~16 iters/thread ----
    for (int e = gid; e < NE; e += 49 * 1024) {
        int d = __builtin_nontemporal_load(dst + e);
        int r = __builtin_nontemporal_load(rank + e);
        int s = __builtin_nontemporal_load(src + e);
        float w = __builtin_nontemporal_load(ew + e);
        int rep = (e >> 6) & 3;
        int4 q = rp4[d];
        int off = (rep == 0) ? q.x : (rep == 1) ? q.y : (rep == 2) ? q.z : q.w;
        epk[off + r] = make_int2(s, __float_as_int(w));
    }
}

// gather0: xb bf16 [NN][128] -> aggb bf16 [NN][128] (scaled by dinv).
// 1 wave/node, 128-thr blocks. 8-edge batches (8 row loads in flight).
__global__ __launch_bounds__(128) void k_gather0(const unsigned short* __restrict__ xb,
                                                 const int* __restrict__ rp,
                                                 const int2* __restrict__ epk,
                                                 const float* __restrict__ dinv,
                                                 unsigned short* __restrict__ aggb) {
    int wid = (blockIdx.x * 128 + threadIdx.x) >> 6;
    int lane = threadIdx.x & 63;
    if (wid >= NN) return;
    int beg = rp[wid], end = rp[wid + 1];
    float di = dinv[wid];
    float ax = 0.f, ay = 0.f;
    for (int b = beg; b < end; b += 64) {
        int n = min(end - b, 64);
        int2 pk = epk[b + min(lane, n - 1)];
        int j = 0;
        for (; j + 7 < n; j += 8) {
            int s[8];
#pragma unroll
            for (int i = 0; i < 8; ++i) s[i] = __shfl(pk.x, j + i);
            unsigned u[8];
#pragma unroll
            for (int i = 0; i < 8; ++i)
                u[i] = *(const unsigned*)(xb + (size_t)s[i] * 128 + lane * 2);
            float w[8];
#pragma unroll
            for (int i = 0; i < 8; ++i) w[i] = __int_as_float(__shfl(pk.y, j + i));
#pragma unroll
            for (int i = 0; i < 8; ++i) {
                ax += w[i] * b2f((unsigned short)(u[i] & 0xFFFF));
                ay += w[i] * b2f((unsigned short)(u[i] >> 16));
            }
        }
        for (; j + 3 < n; j += 4) {
            int s0 = __shfl(pk.x, j + 0), s1 = __shfl(pk.x, j + 1);
            int s2 = __shfl(pk.x, j + 2), s3 = __shfl(pk.x, j + 3);
            unsigned u0 = *(const unsigned*)(xb + (size_t)s0 * 128 + lane * 2);
            unsigned u1 = *(const unsigned*)(xb + (size_t)s1 * 128 + lane * 2);
            unsigned u2 = *(const unsigned*)(xb + (size_t)s2 * 128 + lane * 2);
            unsigned u3 = *(const unsigned*)(xb + (size_t)s3 * 128 + lane * 2);
            float w0 = __int_as_float(__shfl(pk.y, j + 0));
            float w1 = __int_as_float(__shfl(pk.y, j + 1));
            float w2 = __int_as_float(__shfl(pk.y, j + 2));
            float w3 = __int_as_float(__shfl(pk.y, j + 3));
            ax += w0 * b2f((unsigned short)(u0 & 0xFFFF)) + w1 * b2f((unsigned short)(u1 & 0xFFFF))
                + w2 * b2f((unsigned short)(u2 & 0xFFFF)) + w3 * b2f((unsigned short)(u3 & 0xFFFF));
            ay += w0 * b2f((unsigned short)(u0 >> 16)) + w1 * b2f((unsigned short)(u1 >> 16))
                + w2 * b2f((unsigned short)(u2 >> 16)) + w3 * b2f((unsigned short)(u3 >> 16));
        }
        for (; j < n; ++j) {
            int s = __shfl(pk.x, j);
            float w = __int_as_float(__shfl(pk.y, j));
            unsigned u = *(const unsigned*)(xb + (size_t)s * 128 + lane * 2);
            ax += w * b2f((unsigned short)(u & 0xFFFF));
            ay += w * b2f((unsigned short)(u >> 16));
        }
    }
    __builtin_nontemporal_store(pack2(ax * di, ay * di),
                                (unsigned*)(aggb + (size_t)wid * 128 + lane * 2));
}

// gather1: h1 bf16 [NN][256] -> aggb bf16 [NN][256]. 1 wave/node, 4 ch/lane.
// 128-thr blocks. 8-edge batches.
__global__ __launch_bounds__(128) void k_gather1(const unsigned short* __restrict__ h,
                                                 const int* __restrict__ rp,
                                                 const int2* __restrict__ epk,
                                                 const float* __restrict__ dinv,
                                                 unsigned short* __restrict__ aggb) {
    int wid = (blockIdx.x * 128 + threadIdx.x) >> 6;
    int lane = threadIdx.x & 63;
    if (wid >= NN) return;
    int beg = rp[wid], end = rp[wid + 1];
    float di = dinv[wid];
    float a0 = 0.f, a1 = 0.f, a2 = 0.f, a3 = 0.f;
    for (int b = beg; b < end; b += 64) {
        int n = min(end - b, 64);
        int2 pk = epk[b + min(lane, n - 1)];
        int j = 0;
        for (; j + 7 < n; j += 8) {
            int s[8];
#pragma unroll
            for (int i = 0; i < 8; ++i) s[i] = __shfl(pk.x, j + i);
            uint2 u[8];
#pragma unroll
            for (int i = 0; i < 8; ++i)
                u[i] = *(const uint2*)(h + (size_t)s[i] * 256 + lane * 4);
            float w[8];
#pragma unroll
            for (int i = 0; i < 8; ++i) w[i] = __int_as_float(__shfl(pk.y, j + i));
#pragma unroll
            for (int i = 0; i < 8; ++i) {
                a0 += w[i] * b2f((unsigned short)(u[i].x & 0xFFFF));
                a1 += w[i] * b2f((unsigned short)(u[i].x >> 16));
                a2 += w[i] * b2f((unsigned short)(u[i].y & 0xFFFF));
                a3 += w[i] * b2f((unsigned short)(u[i].y >> 16));
            }
        }
        for (; j + 3 < n; j += 4) {
            int s0 = __shfl(pk.x, j + 0), s1 = __shfl(pk.x, j + 1);
            int s2 = __shfl(pk.x, j + 2), s3 = __shfl(pk.x, j + 3);
            uint2 u0 = *(const uint2*)(h + (size_t)s0 * 256 + lane * 4);
            uint2 u1 = *(const uint2*)(h + (size_t)s1 * 256 + lane * 4);
            uint2 u2 = *(const uint2*)(h + (size_t)s2 * 256 + lane * 4);
            uint2 u3 = *(const uint2*)(h + (size_t)s3 * 256 + lane * 4);
            float w0 = __int_as_float(__shfl(pk.y, j + 0));
            float w1 = __int_as_float(__shfl(pk.y, j + 1));
            float w2 = __int_as_float(__shfl(pk.y, j + 2));
            float w3 = __int_as_float(__shfl(pk.y, j + 3));
            a0 += w0 * b2f((unsigned short)(u0.x & 0xFFFF)) + w1 * b2f((unsigned short)(u1.x & 0xFFFF))
                + w2 * b2f((unsigned short)(u2.x & 0xFFFF)) + w3 * b2f((unsigned short)(u3.x & 0xFFFF));
            a1 += w0 * b2f((unsigned short)(u0.x >> 16)) + w1 * b2f((unsigned short)(u1.x >> 16))
                + w2 * b2f((unsigned short)(u2.x >> 16)) + w3 * b2f((unsigned short)(u3.x >> 16));
            a2 += w0 * b2f((unsigned short)(u0.y & 0xFFFF)) + w1 * b2f((unsigned short)(u1.y & 0xFFFF))
                + w2 * b2f((unsigned short)(u2.y & 0xFFFF)) + w3 * b2f((unsigned short)(u3.y & 0xFFFF));
            a3 += w0 * b2f((unsigned short)(u0.y >> 16)) + w1 * b2f((unsigned short)(u1.y >> 16))
                + w2 * b2f((unsigned short)(u2.y >> 16)) + w3 * b2f((unsigned short)(u3.y >> 16));
        }
        for (; j < n; ++j) {
            int s = __shfl(pk.x, j);
            float w = __int_as_float(__shfl(pk.y, j));
            uint2 u = *(const uint2*)(h + (size_t)s * 256 + lane * 4);
            a0 += w * b2f((unsigned short)(u.x & 0xFFFF));
            a1 += w * b2f((unsigned short)(u.x >> 16));
            a2 += w * b2f((unsigned short)(u.y & 0xFFFF));
            a3 += w * b2f((unsigned short)(u.y >> 16));
        }
    }
    nu2 o;
    o.x = pack2(a0 * di, a1 * di);
    o.y = pack2(a2 * di, a3 * di);
    __builtin_nontemporal_store(o, (nu2*)(aggb + (size_t)wid * 256 + lane * 4));
}

// MFMA GEMM: C[row, 0:256] = concat(Aagg[row,:], Aself[row,:]) @ Bt^T + bias.
// 128x256 (full-N) tile per block, 512 threads / 8 waves (4M x 2N).
template <int K0, bool OUT_F32, bool RELU>
__global__ __launch_bounds__(512) void k_mfma2(const unsigned short* __restrict__ Aagg,
                                               const unsigned short* __restrict__ Aself,
                                               const unsigned short* __restrict__ Bt,
                                               const float* __restrict__ bias,
                                               void* __restrict__ outp) {
    __shared__ unsigned short As[128 * 32];
    __shared__ unsigned short Bs[256 * 32];
    const int tid = threadIdx.x;
    const int m0 = blockIdx.x * 128;
    const int K = 2 * K0;
    const int lane = tid & 63;
    const int w = tid >> 6;
    const int wr = w >> 1, wc = w & 1;          // 4 M-waves x 2 N-waves
    const int fr = lane & 15, fq = lane >> 4;
    const int srowA = tid >> 2;                  // 0..127
    const int sckA = (tid & 3) * 8;              // k-chunk of 8
    const int srowB = tid >> 1;                  // 0..255
    const int sckB = (tid & 1) * 16;             // two uint4: k and k+8

    v4f acc[2][8];
#pragma unroll
    for (int mi = 0; mi < 2; ++mi)
#pragma unroll
        for (int ni = 0; ni < 8; ++ni)
            acc[mi][ni] = (v4f){0.f, 0.f, 0.f, 0.f};

    for (int k0 = 0; k0 < K; k0 += 32) {
        // register-stage global loads
        const int kkA = k0 + sckA;
        const unsigned short* Asrc = (kkA < K0) ? Aagg : (Aself - K0);
        const int rA = m0 + srowA;
        uint4 av = make_uint4(0, 0, 0, 0);
        if (rA < NN) av = *(const uint4*)(Asrc + (size_t)rA * K0 + kkA);
        uint4 bv0 = *(const uint4*)(Bt + (size_t)srowB * K + k0 + sckB);
        uint4 bv1 = *(const uint4*)(Bt + (size_t)srowB * K + k0 + sckB + 8);

        __syncthreads();
        *(uint4*)(As + srowA * 32 + sckA) = av;
        *(uint4*)(Bs + srowB * 32 + sckB) = bv0;
        *(uint4*)(Bs + srowB * 32 + sckB + 8) = bv1;
        __syncthreads();

        v8bf a[2], b[8];
#pragma unroll
        for (int mi = 0; mi < 2; ++mi)
            a[mi] = *(const v8bf*)(As + (wr * 32 + mi * 16 + fr) * 32 + fq * 8);
#pragma unroll
        for (int ni = 0; ni < 8; ++ni)
            b[ni] = *(const v8bf*)(Bs + (wc * 128 + ni * 16 + fr) * 32 + fq * 8);
#pragma unroll
        for (int mi = 0; mi < 2; ++mi)
#pragma unroll
            for (int ni = 0; ni < 8; ++ni)
                acc[mi][ni] = __builtin_amdgcn_mfma_f32_16x16x32_bf16(a[mi], b[ni], acc[mi][ni], 0, 0, 0);
    }

#pragma unroll
    for (int mi = 0; mi < 2; ++mi) {
#pragma unroll
        for (int ni = 0; ni < 8; ++ni) {
            const int col = wc * 128 + ni * 16 + fr;
            const float bb = bias[col];
#pragma unroll
            for (int r = 0; r < 4; ++r) {
                const int row = m0 + wr * 32 + mi * 16 + fq * 4 + r;
                if (row < NN) {
                    float v = acc[mi][ni][r] + bb;
                    if (RELU) v = fmaxf(v, 0.f);
                    if (OUT_F32)
                        __builtin_nontemporal_store(v, &((float*)outp)[(size_t)row * 256 + col]);
                    else
                        ((unsigned short*)outp)[(size_t)row * 256 + col] = f2b(v);
                }
            }
        }
    }
}

extern "C" void kernel_launch(void* const* d_in, const int* in_sizes, int n_in,
                              void* d_out, int out_size, void* d_ws, size_t ws_size,
                              hipStream_t stream) {
    const float* x   = (const float*)d_in[0];
    const int*   ei  = (const int*)d_in[1];
    const float* ew  = (const float*)d_in[2];
    const float* Wl0 = (const float*)d_in[3];
    const float* Wr0 = (const float*)d_in[4];
    const float* b0  = (const float*)d_in[5];
    const float* Wl1 = (const float*)d_in[6];
    const float* Wr1 = (const float*)d_in[7];
    const float* b1  = (const float*)d_in[8];
    float* out = (float*)d_out;

    const int* src = ei;
    const int* dst = ei + NE;

    // ws layout (bytes), total ~58.6 MB (unchanged):
    //   0        dinv  f32[50000]
    //   409600   rp    int[50001]
    //   614400   epk   int2[800000]
    //   7014400  Bt0   bf16[256*256]
    //   7145472  Bt1   bf16[256*512]
    //   7407616  h1b   bf16[50000*256]; head aliases scratch dead before
    //            mfma0 writes h1b: rank int[800000] @ +0 (3.2MB),
    //            cnt4 int[4*50048]+bsum(+done @ bsum[63]) @ +3,200,000,
    //            rp4 int4[50000] @ +4,224,000.
    //   33007616 aggb  bf16[50000*256]; layer0: agg=[NN][128], xb in 2nd half
    char* ws = (char*)d_ws;
    float*          dinv = (float*)(ws + 0);
    int*            rp   = (int*)(ws + 409600);
    int2*           epk  = (int2*)(ws + 614400);
    unsigned short* Bt0  = (unsigned short*)(ws + 7014400);
    unsigned short* Bt1  = (unsigned short*)(ws + 7145472);
    unsigned short* h1b  = (unsigned short*)(ws + 7407616);
    int*            rank = (int*)h1b;
    int*            cnt4 = (int*)((char*)h1b + 3200000);
    int*            bsum = cnt4 + 4 * CREP;
    int4*           rp4  = (int4*)((char*)h1b + 4224000);
    unsigned short* aggb = (unsigned short*)(ws + 33007616);
    unsigned short* xb   = aggb + (size_t)NN * 128;

    (void)hipMemsetAsync(cnt4, 0, 4 * CREP * 4 + 256, stream);  // zeros cnt4 + bsum + done
    k_preph<<<PH_HIST + PH_BT0 + PH_BT1 + PH_XB, 256, 0, stream>>>(
        x, Wl0, Wr0, Wl1, Wr1, dst, cnt4, rank, Bt0, Bt1, xb);
    k_scanbkt<<<49, 1024, 0, stream>>>(cnt4, bsum, rp, rp4, dinv, src, dst, ew, rank, epk);

    const int gm = (NN + 127) / 128;
    const int gg = (NN * 64 + 127) / 128;
    // layer 0
    k_gather0<<<gg, 128, 0, stream>>>(xb, rp, (const int2*)epk, dinv, aggb);
    k_mfma2<128, false, true><<<gm, 512, 0, stream>>>(aggb, xb, Bt0, b0, h1b);
    // layer 1
    k_gather1<<<gg, 128, 0, stream>>>(h1b, rp, (const int2*)epk, dinv, aggb);
    k_mfma2<256, true, false><<<gm, 512, 0, stream>>>(aggb, h1b, Bt1, b1, out);
}

// Round 11
// 311.634 us; speedup vs baseline: 1.2577x; 1.2040x over previous
//
#include <hip/hip_runtime.h>

// GraphSAGE 2-layer. N=50000, E=800000, 128 -> 256 -> 256.
// Round 20: revert round-19 merge (scanbkt=106us: 49-block bucket at 7% occ).
// Back to round-14 structure. One change: k_scanf's serial poll chain (block
// b polls b flags sequentially -> ~29us at block 48) replaced by a 2-kernel
// scan: k_scan1 (block sums + LDS scan -> escan/bsum, no atomics) and
// k_scan2 (wave-shfl scan of 49 sums, emit rp/rp4/dinv). Bucket unchanged.

#define NN 50000
#define NE 800000

typedef __bf16 v8bf __attribute__((ext_vector_type(8)));
typedef float v4f __attribute__((ext_vector_type(4)));
typedef float nf4 __attribute__((ext_vector_type(4)));
typedef unsigned nu2 __attribute__((ext_vector_type(2)));

__device__ __forceinline__ unsigned short f2b(float f) {
    unsigned u = __float_as_uint(f);
    return (unsigned short)((u + 0x7FFFu + ((u >> 16) & 1u)) >> 16);
}
__device__ __forceinline__ float b2f(unsigned short h) {
    return __uint_as_float(((unsigned)h) << 16);
}
__device__ __forceinline__ unsigned pack2(float a, float b) {
    return (unsigned)f2b(a) | ((unsigned)f2b(b) << 16);
}

// Fused hist + prep. Sections by blockIdx (256 threads each), hist FIRST so
// its atomic-bound phase overlaps the streaming casts behind it.
#define PH_HIST 782
#define PH_BT0 256
#define PH_BT1 512
#define PH_XB  6250
#define CREP 50048
__global__ __launch_bounds__(256) void k_preph(const float* __restrict__ x,
                                               const float* __restrict__ Wl0,
                                               const float* __restrict__ Wr0,
                                               const float* __restrict__ Wl1,
                                               const float* __restrict__ Wr1,
                                               const int* __restrict__ dst,
                                               int* __restrict__ cnt4,
                                               int* __restrict__ rank,
                                               unsigned short* __restrict__ Bt0,
                                               unsigned short* __restrict__ Bt1,
                                               unsigned short* __restrict__ xb) {
    int b = blockIdx.x;
    int tid = threadIdx.x;
    if (b < PH_HIST) {
        int e = b * 1024 + tid;                         // 4 edges/thread, stride 256
        int* cr = cnt4 + ((tid >> 6) & 3) * CREP;       // replica = (e>>6)&3
        if (e + 768 < NE) {
            int d0 = __builtin_nontemporal_load(dst + e);
            int d1 = __builtin_nontemporal_load(dst + e + 256);
            int d2 = __builtin_nontemporal_load(dst + e + 512);
            int d3 = __builtin_nontemporal_load(dst + e + 768);
            int p0 = atomicAdd(&cr[d0], 1);
            int p1 = atomicAdd(&cr[d1], 1);
            int p2 = atomicAdd(&cr[d2], 1);
            int p3 = atomicAdd(&cr[d3], 1);
            __builtin_nontemporal_store(p0, rank + e);
            __builtin_nontemporal_store(p1, rank + e + 256);
            __builtin_nontemporal_store(p2, rank + e + 512);
            __builtin_nontemporal_store(p3, rank + e + 768);
        } else {
#pragma unroll
            for (int i = 0; i < 4; ++i) {
                int ee = e + i * 256;
                if (ee < NE) {
                    int d = __builtin_nontemporal_load(dst + ee);
                    int pos = atomicAdd(&cr[d], 1);
                    __builtin_nontemporal_store(pos, rank + ee);
                }
            }
        }
    } else if (b < PH_HIST + PH_BT0) {
        int idx = (b - PH_HIST) * 256 + tid;            // [0, 65536)
        int n = idx >> 8, k = idx & 255;
        float v = (k < 128) ? Wl0[(size_t)k * 256 + n] : Wr0[(size_t)(k - 128) * 256 + n];
        Bt0[idx] = f2b(v);
    } else if (b < PH_HIST + PH_BT0 + PH_BT1) {
        int idx = (b - PH_HIST - PH_BT0) * 256 + tid;   // [0, 131072)
        int n = idx >> 9, k = idx & 511;
        float v = (k < 256) ? Wl1[(size_t)k * 256 + n] : Wr1[(size_t)(k - 256) * 256 + n];
        Bt1[idx] = f2b(v);
    } else {
        int i4 = (b - PH_HIST - PH_BT0 - PH_BT1) * 256 + tid;  // [0, 1.6M)
        nf4 v = __builtin_nontemporal_load((const nf4*)x + i4);
        nu2 o;
        o.x = pack2(v.x, v.y);
        o.y = pack2(v.z, v.w);
        *((nu2*)xb + i4) = o;
    }
}

// Scan pass 1: 49 blocks x 1024. Sum 4 replicas, per-block LDS inclusive
// scan. Write escan[gid] (inclusive-within-block) and bsum[b]. No atomics.
__global__ __launch_bounds__(1024) void k_scan1(const int* __restrict__ cnt4,
                                                int* __restrict__ escan,
                                                int* __restrict__ bsum) {
    __shared__ int tmp[1024];
    const int b = blockIdx.x, tid = threadIdx.x;
    const int gid = b * 1024 + tid;
    int v = 0;
    if (gid < NN) {
        v = cnt4[gid] + cnt4[CREP + gid] + cnt4[2 * CREP + gid] + cnt4[3 * CREP + gid];
    }
    tmp[tid] = v;
    __syncthreads();
    for (int off = 1; off < 1024; off <<= 1) {
        int t = (tid >= off) ? tmp[tid - off] : 0;
        __syncthreads();
        tmp[tid] += t;
        __syncthreads();
    }
    escan[gid] = tmp[tid];
    if (tid == 1023) bsum[b] = tmp[1023];
}

// Scan pass 2: 49 blocks x 1024. Wave 0 shfl-scans the 49 block sums; all
// threads emit rp, rp4, dinv from escan + cnt4 re-read.
__global__ __launch_bounds__(1024) void k_scan2(const int* __restrict__ cnt4,
                                                const int* __restrict__ escan,
                                                const int* __restrict__ bsum,
                                                int* __restrict__ rp,
                                                int4* __restrict__ rp4,
                                                float* __restrict__ dinv) {
    __shared__ int s_off;
    const int b = blockIdx.x, tid = threadIdx.x;
    const int gid = b * 1024 + tid;
    if (tid < 64) {
        int lane = tid;
        int s = (lane < 49) ? bsum[lane] : 0;
#pragma unroll
        for (int off = 1; off < 64; off <<= 1) {
            int t = __shfl_up(s, off);
            if (lane >= off) s += t;
        }
        int so = __shfl(s, (b > 0) ? (b - 1) : 0);
        if (tid == 0) s_off = (b > 0) ? so : 0;
    }
    __syncthreads();
    const int off = s_off;
    if (gid < NN) {
        int c0 = cnt4[gid];
        int c1 = cnt4[CREP + gid];
        int c2 = cnt4[2 * CREP + gid];
        int c3 = cnt4[3 * CREP + gid];
        int v = c0 + c1 + c2 + c3;
        int base = escan[gid] - v + off;
        rp[gid] = base;
        rp4[gid] = make_int4(base, base + c0, base + c0 + c1, base + c0 + c1 + c2);
        dinv[gid] = 1.0f / fmaxf((float)v, 1.0f);
    }
    if (gid == 0) rp[NN] = NE;
}

// Atomic-free bucket: pos = rp4[dst].sel(replica) + rank. 4 edges/thread.
__global__ __launch_bounds__(256) void k_bucket(const int* __restrict__ src,
                                                const int* __restrict__ dst,
                                                const float* __restrict__ ew,
                                                const int* __restrict__ rank,
                                                const int4* __restrict__ rp4,
                                                int2* __restrict__ epk) {
    int base = blockIdx.x * 1024 + threadIdx.x;
    int rep = (threadIdx.x >> 6) & 3;                    // == (e>>6)&3 for all i
#pragma unroll
    for (int i = 0; i < 4; ++i) {
        int e = base + i * 256;
        if (e < NE) {
            int d = __builtin_nontemporal_load(dst + e);
            int r = __builtin_nontemporal_load(rank + e);
            int s = __builtin_nontemporal_load(src + e);
            float w = __builtin_nontemporal_load(ew + e);
            int4 q = rp4[d];
            int off = (rep == 0) ? q.x : (rep == 1) ? q.y : (rep == 2) ? q.z : q.w;
            epk[off + r] = make_int2(s, __float_as_int(w));
        }
    }
}

// gather0: xb bf16 [NN][128] -> aggb bf16 [NN][128] (scaled by dinv).
// 1 wave/node, 128-thr blocks. 8-edge batches (8 row loads in flight).
__global__ __launch_bounds__(128) void k_gather0(const unsigned short* __restrict__ xb,
                                                 const int* __restrict__ rp,
                                                 const int2* __restrict__ epk,
                                                 const float* __restrict__ dinv,
                                                 unsigned short* __restrict__ aggb) {
    int wid = (blockIdx.x * 128 + threadIdx.x) >> 6;
    int lane = threadIdx.x & 63;
    if (wid >= NN) return;
    int beg = rp[wid], end = rp[wid + 1];
    float di = dinv[wid];
    float ax = 0.f, ay = 0.f;
    for (int b = beg; b < end; b += 64) {
        int n = min(end - b, 64);
        int2 pk = epk[b + min(lane, n - 1)];
        int j = 0;
        for (; j + 7 < n; j += 8) {
            int s[8];
#pragma unroll
            for (int i = 0; i < 8; ++i) s[i] = __shfl(pk.x, j + i);
            unsigned u[8];
#pragma unroll
            for (int i = 0; i < 8; ++i)
                u[i] = *(const unsigned*)(xb + (size_t)s[i] * 128 + lane * 2);
            float w[8];
#pragma unroll
            for (int i = 0; i < 8; ++i) w[i] = __int_as_float(__shfl(pk.y, j + i));
#pragma unroll
            for (int i = 0; i < 8; ++i) {
                ax += w[i] * b2f((unsigned short)(u[i] & 0xFFFF));
                ay += w[i] * b2f((unsigned short)(u[i] >> 16));
            }
        }
        for (; j + 3 < n; j += 4) {
            int s0 = __shfl(pk.x, j + 0), s1 = __shfl(pk.x, j + 1);
            int s2 = __shfl(pk.x, j + 2), s3 = __shfl(pk.x, j + 3);
            unsigned u0 = *(const unsigned*)(xb + (size_t)s0 * 128 + lane * 2);
            unsigned u1 = *(const unsigned*)(xb + (size_t)s1 * 128 + lane * 2);
            unsigned u2 = *(const unsigned*)(xb + (size_t)s2 * 128 + lane * 2);
            unsigned u3 = *(const unsigned*)(xb + (size_t)s3 * 128 + lane * 2);
            float w0 = __int_as_float(__shfl(pk.y, j + 0));
            float w1 = __int_as_float(__shfl(pk.y, j + 1));
            float w2 = __int_as_float(__shfl(pk.y, j + 2));
            float w3 = __int_as_float(__shfl(pk.y, j + 3));
            ax += w0 * b2f((unsigned short)(u0 & 0xFFFF)) + w1 * b2f((unsigned short)(u1 & 0xFFFF))
                + w2 * b2f((unsigned short)(u2 & 0xFFFF)) + w3 * b2f((unsigned short)(u3 & 0xFFFF));
            ay += w0 * b2f((unsigned short)(u0 >> 16)) + w1 * b2f((unsigned short)(u1 >> 16))
                + w2 * b2f((unsigned short)(u2 >> 16)) + w3 * b2f((unsigned short)(u3 >> 16));
        }
        for (; j < n; ++j) {
            int s = __shfl(pk.x, j);
            float w = __int_as_float(__shfl(pk.y, j));
            unsigned u = *(const unsigned*)(xb + (size_t)s * 128 + lane * 2);
            ax += w * b2f((unsigned short)(u & 0xFFFF));
            ay += w * b2f((unsigned short)(u >> 16));
        }
    }
    __builtin_nontemporal_store(pack2(ax * di, ay * di),
                                (unsigned*)(aggb + (size_t)wid * 128 + lane * 2));
}

// gather1: h1 bf16 [NN][256] -> aggb bf16 [NN][256]. 1 wave/node, 4 ch/lane.
// 128-thr blocks. 8-edge batches.
__global__ __launch_bounds__(128) void k_gather1(const unsigned short* __restrict__ h,
                                                 const int* __restrict__ rp,
                                                 const int2* __restrict__ epk,
                                                 const float* __restrict__ dinv,
                                                 unsigned short* __restrict__ aggb) {
    int wid = (blockIdx.x * 128 + threadIdx.x) >> 6;
    int lane = threadIdx.x & 63;
    if (wid >= NN) return;
    int beg = rp[wid], end = rp[wid + 1];
    float di = dinv[wid];
    float a0 = 0.f, a1 = 0.f, a2 = 0.f, a3 = 0.f;
    for (int b = beg; b < end; b += 64) {
        int n = min(end - b, 64);
        int2 pk = epk[b + min(lane, n - 1)];
        int j = 0;
        for (; j + 7 < n; j += 8) {
            int s[8];
#pragma unroll
            for (int i = 0; i < 8; ++i) s[i] = __shfl(pk.x, j + i);
            uint2 u[8];
#pragma unroll
            for (int i = 0; i < 8; ++i)
                u[i] = *(const uint2*)(h + (size_t)s[i] * 256 + lane * 4);
            float w[8];
#pragma unroll
            for (int i = 0; i < 8; ++i) w[i] = __int_as_float(__shfl(pk.y, j + i));
#pragma unroll
            for (int i = 0; i < 8; ++i) {
                a0 += w[i] * b2f((unsigned short)(u[i].x & 0xFFFF));
                a1 += w[i] * b2f((unsigned short)(u[i].x >> 16));
                a2 += w[i] * b2f((unsigned short)(u[i].y & 0xFFFF));
                a3 += w[i] * b2f((unsigned short)(u[i].y >> 16));
            }
        }
        for (; j + 3 < n; j += 4) {
            int s0 = __shfl(pk.x, j + 0), s1 = __shfl(pk.x, j + 1);
            int s2 = __shfl(pk.x, j + 2), s3 = __shfl(pk.x, j + 3);
            uint2 u0 = *(const uint2*)(h + (size_t)s0 * 256 + lane * 4);
            uint2 u1 = *(const uint2*)(h + (size_t)s1 * 256 + lane * 4);
            uint2 u2 = *(const uint2*)(h + (size_t)s2 * 256 + lane * 4);
            uint2 u3 = *(const uint2*)(h + (size_t)s3 * 256 + lane * 4);
            float w0 = __int_as_float(__shfl(pk.y, j + 0));
            float w1 = __int_as_float(__shfl(pk.y, j + 1));
            float w2 = __int_as_float(__shfl(pk.y, j + 2));
            float w3 = __int_as_float(__shfl(pk.y, j + 3));
            a0 += w0 * b2f((unsigned short)(u0.x & 0xFFFF)) + w1 * b2f((unsigned short)(u1.x & 0xFFFF))
                + w2 * b2f((unsigned short)(u2.x & 0xFFFF)) + w3 * b2f((unsigned short)(u3.x & 0xFFFF));
            a1 += w0 * b2f((unsigned short)(u0.x >> 16)) + w1 * b2f((unsigned short)(u1.x >> 16))
                + w2 * b2f((unsigned short)(u2.x >> 16)) + w3 * b2f((unsigned short)(u3.x >> 16));
            a2 += w0 * b2f((unsigned short)(u0.y & 0xFFFF)) + w1 * b2f((unsigned short)(u1.y & 0xFFFF))
                + w2 * b2f((unsigned short)(u2.y & 0xFFFF)) + w3 * b2f((unsigned short)(u3.y & 0xFFFF));
            a3 += w0 * b2f((unsigned short)(u0.y >> 16)) + w1 * b2f((unsigned short)(u1.y >> 16))
                + w2 * b2f((unsigned short)(u2.y >> 16)) + w3 * b2f((unsigned short)(u3.y >> 16));
        }
        for (; j < n; ++j) {
            int s = __shfl(pk.x, j);
            float w = __int_as_float(__shfl(pk.y, j));
            uint2 u = *(const uint2*)(h + (size_t)s * 256 + lane * 4);
            a0 += w * b2f((unsigned short)(u.x & 0xFFFF));
            a1 += w * b2f((unsigned short)(u.x >> 16));
            a2 += w * b2f((unsigned short)(u.y & 0xFFFF));
            a3 += w * b2f((unsigned short)(u.y >> 16));
        }
    }
    nu2 o;
    o.x = pack2(a0 * di, a1 * di);
    o.y = pack2(a2 * di, a3 * di);
    __builtin_nontemporal_store(o, (nu2*)(aggb + (size_t)wid * 256 + lane * 4));
}

// MFMA GEMM: C[row, 0:256] = concat(Aagg[row,:], Aself[row,:]) @ Bt^T + bias.
// 128x256 (full-N) tile per block, 512 threads / 8 waves (4M x 2N).
template <int K0, bool OUT_F32, bool RELU>
__global__ __launch_bounds__(512) void k_mfma2(const unsigned short* __restrict__ Aagg,
                                               const unsigned short* __restrict__ Aself,
                                               const unsigned short* __restrict__ Bt,
                                               const float* __restrict__ bias,
                                               void* __restrict__ outp) {
    __shared__ unsigned short As[128 * 32];
    __shared__ unsigned short Bs[256 * 32];
    const int tid = threadIdx.x;
    const int m0 = blockIdx.x * 128;
    const int K = 2 * K0;
    const int lane = tid & 63;
    const int w = tid >> 6;
    const int wr = w >> 1, wc = w & 1;          // 4 M-waves x 2 N-waves
    const int fr = lane & 15, fq = lane >> 4;
    const int srowA = tid >> 2;                  // 0..127
    const int sckA = (tid & 3) * 8;              // k-chunk of 8
    const int srowB = tid >> 1;                  // 0..255
    const int sckB = (tid & 1) * 16;             // two uint4: k and k+8

    v4f acc[2][8];
#pragma unroll
    for (int mi = 0; mi < 2; ++mi)
#pragma unroll
        for (int ni = 0; ni < 8; ++ni)
            acc[mi][ni] = (v4f){0.f, 0.f, 0.f, 0.f};

    for (int k0 = 0; k0 < K; k0 += 32) {
        // register-stage global loads
        const int kkA = k0 + sckA;
        const unsigned short* Asrc = (kkA < K0) ? Aagg : (Aself - K0);
        const int rA = m0 + srowA;
        uint4 av = make_uint4(0, 0, 0, 0);
        if (rA < NN) av = *(const uint4*)(Asrc + (size_t)rA * K0 + kkA);
        uint4 bv0 = *(const uint4*)(Bt + (size_t)srowB * K + k0 + sckB);
        uint4 bv1 = *(const uint4*)(Bt + (size_t)srowB * K + k0 + sckB + 8);

        __syncthreads();
        *(uint4*)(As + srowA * 32 + sckA) = av;
        *(uint4*)(Bs + srowB * 32 + sckB) = bv0;
        *(uint4*)(Bs + srowB * 32 + sckB + 8) = bv1;
        __syncthreads();

        v8bf a[2], b[8];
#pragma unroll
        for (int mi = 0; mi < 2; ++mi)
            a[mi] = *(const v8bf*)(As + (wr * 32 + mi * 16 + fr) * 32 + fq * 8);
#pragma unroll
        for (int ni = 0; ni < 8; ++ni)
            b[ni] = *(const v8bf*)(Bs + (wc * 128 + ni * 16 + fr) * 32 + fq * 8);
#pragma unroll
        for (int mi = 0; mi < 2; ++mi)
#pragma unroll
            for (int ni = 0; ni < 8; ++ni)
                acc[mi][ni] = __builtin_amdgcn_mfma_f32_16x16x32_bf16(a[mi], b[ni], acc[mi][ni], 0, 0, 0);
    }

#pragma unroll
    for (int mi = 0; mi < 2; ++mi) {
#pragma unroll
        for (int ni = 0; ni < 8; ++ni) {
            const int col = wc * 128 + ni * 16 + fr;
            const float bb = bias[col];
#pragma unroll
            for (int r = 0; r < 4; ++r) {
                const int row = m0 + wr * 32 + mi * 16 + fq * 4 + r;
                if (row < NN) {
                    float v = acc[mi][ni][r] + bb;
                    if (RELU) v = fmaxf(v, 0.f);
                    if (OUT_F32)
                        __builtin_nontemporal_store(v, &((float*)outp)[(size_t)row * 256 + col]);
                    else
                        ((unsigned short*)outp)[(size_t)row * 256 + col] = f2b(v);
                }
            }
        }
    }
}

extern "C" void kernel_launch(void* const* d_in, const int* in_sizes, int n_in,
                              void* d_out, int out_size, void* d_ws, size_t ws_size,
                              hipStream_t stream) {
    const float* x   = (const float*)d_in[0];
    const int*   ei  = (const int*)d_in[1];
    const float* ew  = (const float*)d_in[2];
    const float* Wl0 = (const float*)d_in[3];
    const float* Wr0 = (const float*)d_in[4];
    const float* b0  = (const float*)d_in[5];
    const float* Wl1 = (const float*)d_in[6];
    const float* Wr1 = (const float*)d_in[7];
    const float* b1  = (const float*)d_in[8];
    float* out = (float*)d_out;

    const int* src = ei;
    const int* dst = ei + NE;

    // ws layout (bytes), total ~58.6 MB (unchanged):
    //   0        dinv  f32[50000]
    //   409600   rp    int[50001]
    //   614400   epk   int2[800000]
    //   7014400  Bt0   bf16[256*256]
    //   7145472  Bt1   bf16[256*512]
    //   7407616  h1b   bf16[50000*256]; head aliases scratch dead before
    //            mfma0 writes h1b: rank int[800000] @ +0 (3.2MB),
    //            cnt4 int[4*50048]+bsum @ +3,200,000, rp4 int4[50000]
    //            @ +4,224,000, escan int[50176] @ +5,120,000.
    //   33007616 aggb  bf16[50000*256]; layer0: agg=[NN][128], xb in 2nd half
    char* ws = (char*)d_ws;
    float*          dinv = (float*)(ws + 0);
    int*            rp   = (int*)(ws + 409600);
    int2*           epk  = (int2*)(ws + 614400);
    unsigned short* Bt0  = (unsigned short*)(ws + 7014400);
    unsigned short* Bt1  = (unsigned short*)(ws + 7145472);
    unsigned short* h1b  = (unsigned short*)(ws + 7407616);
    int*            rank = (int*)h1b;
    int*            cnt4 = (int*)((char*)h1b + 3200000);
    int*            bsum = cnt4 + 4 * CREP;
    int4*           rp4  = (int4*)((char*)h1b + 4224000);
    int*            escan = (int*)((char*)h1b + 5120000);
    unsigned short* aggb = (unsigned short*)(ws + 33007616);
    unsigned short* xb   = aggb + (size_t)NN * 128;

    (void)hipMemsetAsync(cnt4, 0, 4 * CREP * 4 + 256, stream);  // zeros cnt4 + bsum
    k_preph<<<PH_HIST + PH_BT0 + PH_BT1 + PH_XB, 256, 0, stream>>>(
        x, Wl0, Wr0, Wl1, Wr1, dst, cnt4, rank, Bt0, Bt1, xb);
    k_scan1<<<49, 1024, 0, stream>>>(cnt4, escan, bsum);
    k_scan2<<<49, 1024, 0, stream>>>(cnt4, escan, bsum, rp, rp4, dinv);
    k_bucket<<<(NE + 1023) / 1024, 256, 0, stream>>>(src, dst, ew, rank, rp4, epk);

    const int gm = (NN + 127) / 128;
    const int gg = (NN * 64 + 127) / 128;
    // layer 0
    k_gather0<<<gg, 128, 0, stream>>>(xb, rp, (const int2*)epk, dinv, aggb);
    k_mfma2<128, false, true><<<gm, 512, 0, stream>>>(aggb, xb, Bt0, b0, h1b);
    // layer 1
    k_gather1<<<gg, 128, 0, stream>>>(h1b, rp, (const int2*)epk, dinv, aggb);
    k_mfma2<256, true, false><<<gm, 512, 0, stream>>>(aggb, h1b, Bt1, b1, out);
}